// Round 7
// baseline (1120.738 us; speedup 1.0000x reference)
//
#include <hip/hip_runtime.h>
#include <stdint.h>
#include <stddef.h>

// ---------------------------------------------------------------------------
// MinGRU NLP model forward on MI355X (gfx950).  ALL float I/O is fp32.
// Pipeline: embed -> [LN -> gates GEMM -> scan(+res)] x3 -> LN -> vocab GEMM.
// GEMM: m97 structure (128x128 tile, BK=32, 4 waves, global_load_lds 16B,
// v_mfma_f32_16x16x32_bf16 with SWAPPED operands, fp32 accum).
// MSTRIP: final GEMM blocks cover 4 row-blocks per col-block so the B panel
// is HBM-read once and L2-reused (cuts logical B traffic 4x).
// Epilogue: C staged through LDS -> full 128B-line stores (no partial lines);
// final GEMM uses non-temporal stores for the write-once logit stream.
// Scan: 3-kernel chunked linear recurrence h = a*h + v (32 chunks x 64).
// ---------------------------------------------------------------------------

typedef __attribute__((ext_vector_type(4))) float f32x4;
typedef __attribute__((ext_vector_type(8))) short bf16x8;
typedef float f32x4u __attribute__((vector_size(16), aligned(4)));

__device__ __forceinline__ unsigned short f2bf(float f) {
  unsigned int u = __float_as_uint(f);
  u += 0x7FFFu + ((u >> 16) & 1u);  // RNE
  return (unsigned short)(u >> 16);
}

__device__ __forceinline__ void gload16(const void* g, void* l) {
  __builtin_amdgcn_global_load_lds(
      (const __attribute__((address_space(1))) void*)g,
      (__attribute__((address_space(3))) void*)l, 16, 0, 0);
}

// ---------------------------------------------------------------------------
// fp32 -> bf16 conversion, 8 elems/thread/iter, grid-stride.
__global__ __launch_bounds__(256) void cvt_kernel(
    const float* __restrict__ in, unsigned short* __restrict__ out, int n8) {
  int i = blockIdx.x * 256 + threadIdx.x;
  int stride = gridDim.x * 256;
  for (; i < n8; i += stride) {
    const float4* p = (const float4*)in + (size_t)i * 2;
    float4 a = p[0], b = p[1];
    bf16x8 o;
    o[0] = (short)f2bf(a.x); o[1] = (short)f2bf(a.y);
    o[2] = (short)f2bf(a.z); o[3] = (short)f2bf(a.w);
    o[4] = (short)f2bf(b.x); o[5] = (short)f2bf(b.y);
    o[6] = (short)f2bf(b.z); o[7] = (short)f2bf(b.w);
    *(bf16x8*)(out + (size_t)i * 8) = o;
  }
}

// ---------------------------------------------------------------------------
// Embedding gather + bf16 cast: x_bf[tok, 0:768] = bf16(embW[ids[tok], :])
__global__ __launch_bounds__(256) void embed_kernel(
    const int* __restrict__ ids, const float* __restrict__ embW,
    unsigned short* __restrict__ xbf) {
  int tok = blockIdx.x;
  int id = ids[tok];
  const float* src = embW + (size_t)id * 768;
  unsigned short* dst = xbf + (size_t)tok * 768;
  for (int j = threadIdx.x; j < 768; j += 256) dst[j] = f2bf(src[j]);
}

// ---------------------------------------------------------------------------
// LayerNorm over last dim D (template: fully unrolled), one block per row.
// BF16IN=1: input bf16 bits; else fp32. Weights/bias fp32. Output bf16.
template <int BF16IN, int D>
__global__ __launch_bounds__(256) void ln_kernel(
    const void* __restrict__ xin, const float* __restrict__ w,
    const float* __restrict__ b, unsigned short* __restrict__ xout,
    float eps) {
  constexpr int NV = D / 256;
  int row = blockIdx.x;
  int tid = threadIdx.x;
  int lane = tid & 63, wid = tid >> 6;
  const float* xf = (const float*)xin;
  const unsigned short* xb = (const unsigned short*)xin;
  float vals[NV];
  float s = 0.f, ss = 0.f;
#pragma unroll
  for (int i = 0; i < NV; i++) {
    size_t idx = (size_t)row * D + i * 256 + tid;
    float v;
    if (BF16IN) {
      unsigned int u = ((unsigned int)xb[idx]) << 16;
      v = __uint_as_float(u);
    } else {
      v = xf[idx];
    }
    vals[i] = v;
    s += v;
    ss += v * v;
  }
  for (int off = 32; off; off >>= 1) {
    s += __shfl_down(s, off);
    ss += __shfl_down(ss, off);
  }
  __shared__ float red[8];
  if (lane == 0) { red[wid] = s; red[4 + wid] = ss; }
  __syncthreads();
  s = red[0] + red[1] + red[2] + red[3];
  ss = red[4] + red[5] + red[6] + red[7];
  constexpr float invD = 1.f / (float)D;
  float mu = s * invD;
  float var = ss * invD - mu * mu;
  float inv = rsqrtf(var + eps);
#pragma unroll
  for (int i = 0; i < NV; i++) {
    int col = i * 256 + tid;
    size_t idx = (size_t)row * D + col;
    float y = (vals[i] - mu) * inv * w[col] + b[col];
    xout[idx] = f2bf(y);
  }
}

// ---------------------------------------------------------------------------
// C[M,N] = A[M,K] * B[N,K]^T  (A,B bf16 bits; fp32 accum; fp32 out)
// FINAL=1: add fp32 bias, bound-check tail columns (N=50257), clamp B stage
//          rows, non-temporal FULL-LINE C stores.
// MSTRIP:  row-blocks per block (B panel staged from L2 across strips).
// Grid: dim3(ncb, nrb/MSTRIP), x fastest.
// MFMA is mfma(b_frag, a_frag, acc): lane's f32x4 = 4 consecutive n values,
//   n = cbase + j*16 + (lane>>4)*4 + q,  m = rbase + i*16 + (lane&15).
template <int FINAL, int MSTRIP>
__global__ __launch_bounds__(256) void gemm_bt(
    const unsigned short* __restrict__ A, const unsigned short* __restrict__ B,
    float* __restrict__ C, const float* __restrict__ bias, int M, int N,
    int K) {
  // Union: K-loop staging (16384B) / epilogue C chunk (32x132 f32 = 16896B).
  __shared__ __align__(16) char smem[16896];
  unsigned short* lsA = (unsigned short*)smem;
  unsigned short* lsB = (unsigned short*)(smem + 8192);
  float* lsC = (float*)smem;

  const int tid = threadIdx.x;
  const int lane = tid & 63;
  const int wid = __builtin_amdgcn_readfirstlane(tid >> 6);
  const int col0 = blockIdx.x * 128;

  const int srow = tid >> 2;      // staging row 0..63
  const int skg = (tid & 3) * 8;  // staging k elem offset (16B granules)

  int nB0 = col0 + srow, nB1 = col0 + 64 + srow;
  if (FINAL) { nB0 = min(nB0, N - 1); nB1 = min(nB1, N - 1); }
  const unsigned short* gB0 = B + (size_t)nB0 * K + skg;
  const unsigned short* gB1 = B + (size_t)nB1 * K + skg;

  char* ldsA0 = (char*)lsA + wid * 1024;
  char* ldsA1 = (char*)lsA + 4096 + wid * 1024;
  char* ldsB0 = (char*)lsB + wid * 1024;
  char* ldsB1 = (char*)lsB + 4096 + wid * 1024;

  const int wm = wid >> 1, wn = wid & 1;  // 2x2 waves, 64x64 each
  const unsigned short* pA = lsA + (wm * 64 + (lane & 15)) * 32 + (lane >> 4) * 8;
  const unsigned short* pB = lsB + (wn * 64 + (lane & 15)) * 32 + (lane >> 4) * 8;

  const int mloc = lane & 15;
  const int ng = (lane >> 4) * 4;
  const int LDC = 132;
  const int trow = tid >> 5;        // 0..7
  const int tcol = (tid & 31) * 4;  // 0..124

  for (int s = 0; s < MSTRIP; s++) {
    const int row0 = (blockIdx.y * MSTRIP + s) * 128;
    const unsigned short* gA0 = A + (size_t)(row0 + srow) * K + skg;
    const unsigned short* gA1 = A + (size_t)(row0 + 64 + srow) * K + skg;

    f32x4 acc[4][4] = {};

    for (int k0 = 0; k0 < K; k0 += 32) {
      gload16(gA0 + k0, ldsA0);
      gload16(gA1 + k0, ldsA1);
      gload16(gB0 + k0, ldsB0);
      gload16(gB1 + k0, ldsB1);
      __syncthreads();
      bf16x8 af[4], bfr[4];
#pragma unroll
      for (int i = 0; i < 4; i++) af[i] = *(const bf16x8*)(pA + i * 512);
#pragma unroll
      for (int i = 0; i < 4; i++) bfr[i] = *(const bf16x8*)(pB + i * 512);
#pragma unroll
      for (int i = 0; i < 4; i++)
#pragma unroll
        for (int j = 0; j < 4; j++)
          acc[i][j] = __builtin_amdgcn_mfma_f32_16x16x32_bf16(
              bfr[j], af[i], acc[i][j], 0, 0, 0);
      __syncthreads();
    }

    // ---- Epilogue: LDS transpose -> full-line streaming stores ----
#pragma unroll
    for (int c = 0; c < 4; c++) {
      if (wm == (c >> 1)) {
        const int i0 = 2 * (c & 1);
#pragma unroll
        for (int ii = 0; ii < 2; ii++)
#pragma unroll
          for (int j = 0; j < 4; j++)
            *(f32x4*)(lsC + (ii * 16 + mloc) * LDC + wn * 64 + j * 16 + ng) =
                acc[i0 + ii][j];
      }
      __syncthreads();
#pragma unroll
      for (int rr = 0; rr < 4; rr++) {
        const int r = rr * 8 + trow;
        const size_t gr = row0 + c * 32 + r;
        f32x4 v = *(const f32x4*)(lsC + r * LDC + tcol);
        if (!FINAL) {
          *(f32x4*)(C + gr * N + col0 + tcol) = v;
        } else {
          const int n0 = col0 + tcol;
          if (col0 + 128 <= N) {
            const f32x4u bv = *(const f32x4u*)(bias + n0);
            f32x4u o;
#pragma unroll
            for (int q = 0; q < 4; q++) o[q] = v[q] + bv[q];
            __builtin_nontemporal_store(o, (f32x4u*)(C + gr * N + n0));
          } else {
#pragma unroll
            for (int q = 0; q < 4; q++)
              if (n0 + q < N) C[gr * N + n0 + q] = v[q] + bias[n0 + q];
          }
        }
      }
      __syncthreads();
    }
  }
}

// ---------------------------------------------------------------------------
// MinGRU scan, 3-kernel chunked linear recurrence.
// gh: [B*S, 2048] fp32; gate = col h, hidden = col h+1024.
// h_t = a*h_{t-1} + (1-a)*g(h~),  a = sigmoid(-gate),
// g(x) = x>=0 ? x+0.5 : sigmoid(x),  h_0 = 0.5.
// 32 chunks of 64 steps; channel instance hp = b*1024 + h (2048 total).
__device__ __forceinline__ void gru_step(float gate, float hid, float& a,
                                         float& g) {
  a = 1.f / (1.f + expf(gate));  // sigmoid(-gate)
  g = (hid >= 0.f) ? (hid + 0.5f) : 1.f / (1.f + expf(-hid));
}

__global__ __launch_bounds__(256) void scan_compose(
    const float* __restrict__ gh, float* __restrict__ Acl,
    float* __restrict__ Vcl) {
  int ck = blockIdx.x;                      // chunk 0..31
  int hp = blockIdx.y * 256 + threadIdx.x;  // 0..2047
  int b = hp >> 10, h = hp & 1023;
  const float* gb = gh + ((size_t)(b * 2048 + ck * 64)) * 2048 + h;
  float A = 1.f, V = 0.f;
  for (int t = 0; t < 64; t++) {
    float gate = gb[(size_t)t * 2048];
    float hid = gb[(size_t)t * 2048 + 1024];
    float a, g;
    gru_step(gate, hid, a, g);
    V = a * V + (1.f - a) * g;
    A *= a;
  }
  size_t i = (size_t)(b * 32 + ck) * 1024 + h;
  Acl[i] = A;
  Vcl[i] = V;
}

__global__ __launch_bounds__(256) void scan_prefix(
    const float* __restrict__ Acl, const float* __restrict__ Vcl,
    float* __restrict__ Hin) {
  int hp = blockIdx.x * 256 + threadIdx.x;
  int b = hp >> 10, h = hp & 1023;
  float hr = 0.5f;
  for (int ck = 0; ck < 32; ck++) {
    size_t i = (size_t)(b * 32 + ck) * 1024 + h;
    Hin[i] = hr;
    hr = Acl[i] * hr + Vcl[i];
  }
}

__global__ __launch_bounds__(256) void scan_emit(
    const float* __restrict__ gh, const float* __restrict__ Hin,
    const float* __restrict__ res, float* __restrict__ xout) {
  int ck = blockIdx.x;
  int hp = blockIdx.y * 256 + threadIdx.x;
  int b = hp >> 10, h = hp & 1023;
  const float* gb = gh + ((size_t)(b * 2048 + ck * 64)) * 2048 + h;
  const float* rb = res + ((size_t)(b * 2048 + ck * 64)) * 1024 + h;
  float* ob = xout + ((size_t)(b * 2048 + ck * 64)) * 1024 + h;
  float hc = Hin[(size_t)(b * 32 + ck) * 1024 + h];
  for (int t = 0; t < 64; t++) {
    float gate = gb[(size_t)t * 2048];
    float hid = gb[(size_t)t * 2048 + 1024];
    float a, g;
    gru_step(gate, hid, a, g);
    hc = a * hc + (1.f - a) * g;
    ob[(size_t)t * 1024] = hc + rb[(size_t)t * 1024];
  }
}

// ---------------------------------------------------------------------------
extern "C" void kernel_launch(void* const* d_in, const int* in_sizes, int n_in,
                              void* d_out, int out_size, void* d_ws,
                              size_t ws_size, hipStream_t stream) {
  (void)in_sizes; (void)n_in; (void)out_size; (void)ws_size;
  const int* ids = (const int*)d_in[0];
  const float* embW = (const float*)d_in[1];
  const float* ln0w = (const float*)d_in[2];
  const float* ln0b = (const float*)d_in[3];
  const float* g0W = (const float*)d_in[4];
  const float* ln1w = (const float*)d_in[5];
  const float* ln1b = (const float*)d_in[6];
  const float* g1W = (const float*)d_in[7];
  const float* ln2w = (const float*)d_in[8];
  const float* ln2b = (const float*)d_in[9];
  const float* g2W = (const float*)d_in[10];
  const float* r0W = (const float*)d_in[11];
  const float* lnfw = (const float*)d_in[12];
  const float* lnfb = (const float*)d_in[13];
  const float* fcW = (const float*)d_in[14];
  const float* fcb = (const float*)d_in[15];
  float* out = (float*)d_out;

  const int M = 4096;  // B*S
  const int V = 50257;

  // Workspace layout (~191.3 MB total).
  char* ws = (char*)d_ws;
  unsigned short* x_bf = (unsigned short*)(ws + 0);          //  6,291,456
  float* x_f = (float*)(ws + 6291456);                       // 16,777,216
  unsigned short* xn_bf = (unsigned short*)(ws + 23068672);  //  8,388,608
  float* gh = (float*)(ws + 31457280);                       // 33,554,432
  float* r0 = (float*)(ws + 65011712);                       // 16,777,216
  float* Acl = (float*)(ws + 81788928);                      //    262,144
  float* Vcl = (float*)(ws + 82051072);                      //    262,144
  float* Hin = (float*)(ws + 82313216);                      //    262,144
  unsigned short* gwbf = (unsigned short*)(ws + 82575360);   //  4,194,304
  unsigned short* rwbf = (unsigned short*)(ws + 86769664);   //  1,572,864
  unsigned short* fcwbf = (unsigned short*)(ws + 88342528);  // 102,926,336

  auto cvt = [&](const float* src, unsigned short* dst, int n) {
    int n8 = n / 8;
    int grid = min((n8 + 255) / 256, 2048);
    cvt_kernel<<<grid, 256, 0, stream>>>(src, dst, n8);
  };

  embed_kernel<<<M, 256, 0, stream>>>(ids, embW, x_bf);
  cvt(fcW, fcwbf, V * 1024);
  cvt(r0W, rwbf, 1024 * 768);

  // ---- layer 0 (in 768 -> out 1024, residual = x @ res0_W^T) ----
  cvt(g0W, gwbf, 2048 * 768);
  ln_kernel<1, 768><<<M, 256, 0, stream>>>(x_bf, ln0w, ln0b, xn_bf, 1e-5f);
  gemm_bt<0, 1><<<dim3(16, 32), 256, 0, stream>>>(xn_bf, gwbf, gh, nullptr, M,
                                                  2048, 768);
  gemm_bt<0, 1><<<dim3(8, 32), 256, 0, stream>>>(x_bf, rwbf, r0, nullptr, M,
                                                 1024, 768);
  scan_compose<<<dim3(32, 8), 256, 0, stream>>>(gh, Acl, Vcl);
  scan_prefix<<<8, 256, 0, stream>>>(Acl, Vcl, Hin);
  scan_emit<<<dim3(32, 8), 256, 0, stream>>>(gh, Hin, r0, x_f);

  // ---- layer 1 (identity residual) ----
  cvt(g1W, gwbf, 2048 * 1024);
  ln_kernel<0, 1024><<<M, 256, 0, stream>>>(x_f, ln1w, ln1b, xn_bf, 1e-5f);
  gemm_bt<0, 1><<<dim3(16, 32), 256, 0, stream>>>(xn_bf, gwbf, gh, nullptr, M,
                                                  2048, 1024);
  scan_compose<<<dim3(32, 8), 256, 0, stream>>>(gh, Acl, Vcl);
  scan_prefix<<<8, 256, 0, stream>>>(Acl, Vcl, Hin);
  scan_emit<<<dim3(32, 8), 256, 0, stream>>>(gh, Hin, x_f, x_f);

  // ---- layer 2 (identity residual) ----
  cvt(g2W, gwbf, 2048 * 1024);
  ln_kernel<0, 1024><<<M, 256, 0, stream>>>(x_f, ln2w, ln2b, xn_bf, 1e-5f);
  gemm_bt<0, 1><<<dim3(16, 32), 256, 0, stream>>>(xn_bf, gwbf, gh, nullptr, M,
                                                  2048, 1024);
  scan_compose<<<dim3(32, 8), 256, 0, stream>>>(gh, Acl, Vcl);
  scan_prefix<<<8, 256, 0, stream>>>(Acl, Vcl, Hin);
  scan_emit<<<dim3(32, 8), 256, 0, stream>>>(gh, Hin, x_f, x_f);

  // ---- final LN (eps=0) + vocab GEMM with bias, fp32 out ----
  // MSTRIP=4: each block does 4 row-blocks (512 M rows) for one col-block;
  // grid (393, 8) = 3144 blocks.
  ln_kernel<0, 1024><<<M, 256, 0, stream>>>(x_f, lnfw, lnfb, xn_bf, 0.0f);
  gemm_bt<1, 4><<<dim3((V + 127) / 128, 8), 256, 0, stream>>>(
      xn_bf, fcwbf, out, fcb, M, V, 1024);
}

// Round 8
// 963.414 us; speedup vs baseline: 1.1633x; 1.1633x over previous
//
#include <hip/hip_runtime.h>
#include <stdint.h>
#include <stddef.h>

// ---------------------------------------------------------------------------
// MinGRU NLP model forward on MI355X (gfx950).  ALL float I/O is fp32.
// Pipeline: embed -> [LN -> gates GEMM -> scan(+res)] x3 -> LN -> vocab GEMM.
// GEMM: m97 structure (128x128 tile, BK=32, 4 waves, global_load_lds 16B,
// v_mfma_f32_16x16x32_bf16 with SWAPPED operands, fp32 accum).
// Final GEMM grid is ROW-FASTEST: concurrent blocks span ~32 col-panels ->
// B+A concurrent working set ~16MB, L3-resident; B HBM-fetched once.
// Epilogue: C staged through LDS -> full 128B-line stores; final GEMM uses
// non-temporal stores for the write-once logit stream.
// Scan: 3-kernel chunked linear recurrence h = a*h + v (32 chunks x 64).
// ---------------------------------------------------------------------------

typedef __attribute__((ext_vector_type(4))) float f32x4;
typedef __attribute__((ext_vector_type(8))) short bf16x8;
typedef float f32x4u __attribute__((vector_size(16), aligned(4)));

__device__ __forceinline__ unsigned short f2bf(float f) {
  unsigned int u = __float_as_uint(f);
  u += 0x7FFFu + ((u >> 16) & 1u);  // RNE
  return (unsigned short)(u >> 16);
}

__device__ __forceinline__ void gload16(const void* g, void* l) {
  __builtin_amdgcn_global_load_lds(
      (const __attribute__((address_space(1))) void*)g,
      (__attribute__((address_space(3))) void*)l, 16, 0, 0);
}

// ---------------------------------------------------------------------------
// fp32 -> bf16 conversion, 8 elems/thread/iter, grid-stride.
__global__ __launch_bounds__(256) void cvt_kernel(
    const float* __restrict__ in, unsigned short* __restrict__ out, int n8) {
  int i = blockIdx.x * 256 + threadIdx.x;
  int stride = gridDim.x * 256;
  for (; i < n8; i += stride) {
    const float4* p = (const float4*)in + (size_t)i * 2;
    float4 a = p[0], b = p[1];
    bf16x8 o;
    o[0] = (short)f2bf(a.x); o[1] = (short)f2bf(a.y);
    o[2] = (short)f2bf(a.z); o[3] = (short)f2bf(a.w);
    o[4] = (short)f2bf(b.x); o[5] = (short)f2bf(b.y);
    o[6] = (short)f2bf(b.z); o[7] = (short)f2bf(b.w);
    *(bf16x8*)(out + (size_t)i * 8) = o;
  }
}

// ---------------------------------------------------------------------------
// Embedding gather + bf16 cast: x_bf[tok, 0:768] = bf16(embW[ids[tok], :])
__global__ __launch_bounds__(256) void embed_kernel(
    const int* __restrict__ ids, const float* __restrict__ embW,
    unsigned short* __restrict__ xbf) {
  int tok = blockIdx.x;
  int id = ids[tok];
  const float* src = embW + (size_t)id * 768;
  unsigned short* dst = xbf + (size_t)tok * 768;
  for (int j = threadIdx.x; j < 768; j += 256) dst[j] = f2bf(src[j]);
}

// ---------------------------------------------------------------------------
// LayerNorm over last dim D (template: fully unrolled), one block per row.
// BF16IN=1: input bf16 bits; else fp32. Weights/bias fp32. Output bf16.
template <int BF16IN, int D>
__global__ __launch_bounds__(256) void ln_kernel(
    const void* __restrict__ xin, const float* __restrict__ w,
    const float* __restrict__ b, unsigned short* __restrict__ xout,
    float eps) {
  constexpr int NV = D / 256;
  int row = blockIdx.x;
  int tid = threadIdx.x;
  int lane = tid & 63, wid = tid >> 6;
  const float* xf = (const float*)xin;
  const unsigned short* xb = (const unsigned short*)xin;
  float vals[NV];
  float s = 0.f, ss = 0.f;
#pragma unroll
  for (int i = 0; i < NV; i++) {
    size_t idx = (size_t)row * D + i * 256 + tid;
    float v;
    if (BF16IN) {
      unsigned int u = ((unsigned int)xb[idx]) << 16;
      v = __uint_as_float(u);
    } else {
      v = xf[idx];
    }
    vals[i] = v;
    s += v;
    ss += v * v;
  }
  for (int off = 32; off; off >>= 1) {
    s += __shfl_down(s, off);
    ss += __shfl_down(ss, off);
  }
  __shared__ float red[8];
  if (lane == 0) { red[wid] = s; red[4 + wid] = ss; }
  __syncthreads();
  s = red[0] + red[1] + red[2] + red[3];
  ss = red[4] + red[5] + red[6] + red[7];
  constexpr float invD = 1.f / (float)D;
  float mu = s * invD;
  float var = ss * invD - mu * mu;
  float inv = rsqrtf(var + eps);
#pragma unroll
  for (int i = 0; i < NV; i++) {
    int col = i * 256 + tid;
    size_t idx = (size_t)row * D + col;
    float y = (vals[i] - mu) * inv * w[col] + b[col];
    xout[idx] = f2bf(y);
  }
}

// ---------------------------------------------------------------------------
// C[M,N] = A[M,K] * B[N,K]^T  (A,B bf16 bits; fp32 accum; fp32 out)
// FINAL=1: add fp32 bias, bound-check tail columns (N=50257), clamp B stage
//          rows, non-temporal FULL-LINE C stores.
// ROWFAST=1: blockIdx.x = row-block (fastest), blockIdx.y = col-block, so
//            consecutively-dispatched blocks share one B col-panel.
// MFMA is mfma(b_frag, a_frag, acc): lane's f32x4 = 4 consecutive n values,
//   n = cbase + j*16 + (lane>>4)*4 + q,  m = rbase + i*16 + (lane&15).
// Epilogue stages C through LDS so global stores cover full 128B lines.
template <int FINAL, int ROWFAST>
__global__ __launch_bounds__(256) void gemm_bt(
    const unsigned short* __restrict__ A, const unsigned short* __restrict__ B,
    float* __restrict__ C, const float* __restrict__ bias, int M, int N,
    int K) {
  // Union: K-loop staging (16384B) / epilogue C chunk (32x132 f32 = 16896B).
  __shared__ __align__(16) char smem[16896];
  unsigned short* lsA = (unsigned short*)smem;
  unsigned short* lsB = (unsigned short*)(smem + 8192);
  float* lsC = (float*)smem;

  const int tid = threadIdx.x;
  const int lane = tid & 63;
  const int wid = __builtin_amdgcn_readfirstlane(tid >> 6);
  const int row0 = (ROWFAST ? blockIdx.x : blockIdx.y) * 128;
  const int col0 = (ROWFAST ? blockIdx.y : blockIdx.x) * 128;

  const int srow = tid >> 2;      // staging row 0..63
  const int skg = (tid & 3) * 8;  // staging k elem offset (16B granules)

  int nB0 = col0 + srow, nB1 = col0 + 64 + srow;
  if (FINAL) { nB0 = min(nB0, N - 1); nB1 = min(nB1, N - 1); }
  const unsigned short* gA0 = A + (size_t)(row0 + srow) * K + skg;
  const unsigned short* gA1 = A + (size_t)(row0 + 64 + srow) * K + skg;
  const unsigned short* gB0 = B + (size_t)nB0 * K + skg;
  const unsigned short* gB1 = B + (size_t)nB1 * K + skg;

  char* ldsA0 = (char*)lsA + wid * 1024;
  char* ldsA1 = (char*)lsA + 4096 + wid * 1024;
  char* ldsB0 = (char*)lsB + wid * 1024;
  char* ldsB1 = (char*)lsB + 4096 + wid * 1024;

  const int wm = wid >> 1, wn = wid & 1;  // 2x2 waves, 64x64 each
  const unsigned short* pA = lsA + (wm * 64 + (lane & 15)) * 32 + (lane >> 4) * 8;
  const unsigned short* pB = lsB + (wn * 64 + (lane & 15)) * 32 + (lane >> 4) * 8;

  f32x4 acc[4][4] = {};

  for (int k0 = 0; k0 < K; k0 += 32) {
    gload16(gA0 + k0, ldsA0);
    gload16(gA1 + k0, ldsA1);
    gload16(gB0 + k0, ldsB0);
    gload16(gB1 + k0, ldsB1);
    __syncthreads();
    bf16x8 af[4], bfr[4];
#pragma unroll
    for (int i = 0; i < 4; i++) af[i] = *(const bf16x8*)(pA + i * 512);
#pragma unroll
    for (int i = 0; i < 4; i++) bfr[i] = *(const bf16x8*)(pB + i * 512);
#pragma unroll
    for (int i = 0; i < 4; i++)
#pragma unroll
      for (int j = 0; j < 4; j++)
        acc[i][j] = __builtin_amdgcn_mfma_f32_16x16x32_bf16(bfr[j], af[i],
                                                            acc[i][j], 0, 0, 0);
    __syncthreads();
  }

  // ---- Epilogue: LDS transpose -> full-line streaming stores ----
  // Chunk c covers tile rows [32c, 32c+32). Owner waves: wm == c>>1,
  // local i = 2*(c&1)+ii. LDS stride 132 floats (528B): conflict-free.
  const int mloc = lane & 15;
  const int ng = (lane >> 4) * 4;
  const int LDC = 132;
  const int trow = tid >> 5;        // 0..7
  const int tcol = (tid & 31) * 4;  // 0..124
#pragma unroll
  for (int c = 0; c < 4; c++) {
    if (wm == (c >> 1)) {
      const int i0 = 2 * (c & 1);
#pragma unroll
      for (int ii = 0; ii < 2; ii++)
#pragma unroll
        for (int j = 0; j < 4; j++)
          *(f32x4*)(lsC + (ii * 16 + mloc) * LDC + wn * 64 + j * 16 + ng) =
              acc[i0 + ii][j];
    }
    __syncthreads();
    // Stream 32x128 chunk: each wave-instruction writes 2 full rows x 512B.
#pragma unroll
    for (int rr = 0; rr < 4; rr++) {
      const int r = rr * 8 + trow;
      const size_t gr = row0 + c * 32 + r;
      f32x4 v = *(const f32x4*)(lsC + r * LDC + tcol);
      if (!FINAL) {
        *(f32x4*)(C + gr * N + col0 + tcol) = v;
      } else {
        const int n0 = col0 + tcol;
        if (col0 + 128 <= N) {
          const f32x4u bv = *(const f32x4u*)(bias + n0);
          f32x4u o;
#pragma unroll
          for (int q = 0; q < 4; q++) o[q] = v[q] + bv[q];
          __builtin_nontemporal_store(o, (f32x4u*)(C + gr * N + n0));
        } else {
#pragma unroll
          for (int q = 0; q < 4; q++)
            if (n0 + q < N) C[gr * N + n0 + q] = v[q] + bias[n0 + q];
        }
      }
    }
    __syncthreads();
  }
}

// ---------------------------------------------------------------------------
// MinGRU scan, 3-kernel chunked linear recurrence.
// gh: [B*S, 2048] fp32; gate = col h, hidden = col h+1024.
// h_t = a*h_{t-1} + (1-a)*g(h~),  a = sigmoid(-gate),
// g(x) = x>=0 ? x+0.5 : sigmoid(x),  h_0 = 0.5.
// 32 chunks of 64 steps; channel instance hp = b*1024 + h (2048 total).
__device__ __forceinline__ void gru_step(float gate, float hid, float& a,
                                         float& g) {
  a = 1.f / (1.f + expf(gate));  // sigmoid(-gate)
  g = (hid >= 0.f) ? (hid + 0.5f) : 1.f / (1.f + expf(-hid));
}

__global__ __launch_bounds__(256) void scan_compose(
    const float* __restrict__ gh, float* __restrict__ Acl,
    float* __restrict__ Vcl) {
  int ck = blockIdx.x;                      // chunk 0..31
  int hp = blockIdx.y * 256 + threadIdx.x;  // 0..2047
  int b = hp >> 10, h = hp & 1023;
  const float* gb = gh + ((size_t)(b * 2048 + ck * 64)) * 2048 + h;
  float A = 1.f, V = 0.f;
  for (int t = 0; t < 64; t++) {
    float gate = gb[(size_t)t * 2048];
    float hid = gb[(size_t)t * 2048 + 1024];
    float a, g;
    gru_step(gate, hid, a, g);
    V = a * V + (1.f - a) * g;
    A *= a;
  }
  size_t i = (size_t)(b * 32 + ck) * 1024 + h;
  Acl[i] = A;
  Vcl[i] = V;
}

__global__ __launch_bounds__(256) void scan_prefix(
    const float* __restrict__ Acl, const float* __restrict__ Vcl,
    float* __restrict__ Hin) {
  int hp = blockIdx.x * 256 + threadIdx.x;
  int b = hp >> 10, h = hp & 1023;
  float hr = 0.5f;
  for (int ck = 0; ck < 32; ck++) {
    size_t i = (size_t)(b * 32 + ck) * 1024 + h;
    Hin[i] = hr;
    hr = Acl[i] * hr + Vcl[i];
  }
}

__global__ __launch_bounds__(256) void scan_emit(
    const float* __restrict__ gh, const float* __restrict__ Hin,
    const float* __restrict__ res, float* __restrict__ xout) {
  int ck = blockIdx.x;
  int hp = blockIdx.y * 256 + threadIdx.x;
  int b = hp >> 10, h = hp & 1023;
  const float* gb = gh + ((size_t)(b * 2048 + ck * 64)) * 2048 + h;
  const float* rb = res + ((size_t)(b * 2048 + ck * 64)) * 1024 + h;
  float* ob = xout + ((size_t)(b * 2048 + ck * 64)) * 1024 + h;
  float hc = Hin[(size_t)(b * 32 + ck) * 1024 + h];
  for (int t = 0; t < 64; t++) {
    float gate = gb[(size_t)t * 2048];
    float hid = gb[(size_t)t * 2048 + 1024];
    float a, g;
    gru_step(gate, hid, a, g);
    hc = a * hc + (1.f - a) * g;
    ob[(size_t)t * 1024] = hc + rb[(size_t)t * 1024];
  }
}

// ---------------------------------------------------------------------------
extern "C" void kernel_launch(void* const* d_in, const int* in_sizes, int n_in,
                              void* d_out, int out_size, void* d_ws,
                              size_t ws_size, hipStream_t stream) {
  (void)in_sizes; (void)n_in; (void)out_size; (void)ws_size;
  const int* ids = (const int*)d_in[0];
  const float* embW = (const float*)d_in[1];
  const float* ln0w = (const float*)d_in[2];
  const float* ln0b = (const float*)d_in[3];
  const float* g0W = (const float*)d_in[4];
  const float* ln1w = (const float*)d_in[5];
  const float* ln1b = (const float*)d_in[6];
  const float* g1W = (const float*)d_in[7];
  const float* ln2w = (const float*)d_in[8];
  const float* ln2b = (const float*)d_in[9];
  const float* g2W = (const float*)d_in[10];
  const float* r0W = (const float*)d_in[11];
  const float* lnfw = (const float*)d_in[12];
  const float* lnfb = (const float*)d_in[13];
  const float* fcW = (const float*)d_in[14];
  const float* fcb = (const float*)d_in[15];
  float* out = (float*)d_out;

  const int M = 4096;  // B*S
  const int V = 50257;

  // Workspace layout (~191.3 MB total).
  char* ws = (char*)d_ws;
  unsigned short* x_bf = (unsigned short*)(ws + 0);          //  6,291,456
  float* x_f = (float*)(ws + 6291456);                       // 16,777,216
  unsigned short* xn_bf = (unsigned short*)(ws + 23068672);  //  8,388,608
  float* gh = (float*)(ws + 31457280);                       // 33,554,432
  float* r0 = (float*)(ws + 65011712);                       // 16,777,216
  float* Acl = (float*)(ws + 81788928);                      //    262,144
  float* Vcl = (float*)(ws + 82051072);                      //    262,144
  float* Hin = (float*)(ws + 82313216);                      //    262,144
  unsigned short* gwbf = (unsigned short*)(ws + 82575360);   //  4,194,304
  unsigned short* rwbf = (unsigned short*)(ws + 86769664);   //  1,572,864
  unsigned short* fcwbf = (unsigned short*)(ws + 88342528);  // 102,926,336

  auto cvt = [&](const float* src, unsigned short* dst, int n) {
    int n8 = n / 8;
    int grid = min((n8 + 255) / 256, 2048);
    cvt_kernel<<<grid, 256, 0, stream>>>(src, dst, n8);
  };

  embed_kernel<<<M, 256, 0, stream>>>(ids, embW, x_bf);
  cvt(fcW, fcwbf, V * 1024);
  cvt(r0W, rwbf, 1024 * 768);

  // ---- layer 0 (in 768 -> out 1024, residual = x @ res0_W^T) ----
  cvt(g0W, gwbf, 2048 * 768);
  ln_kernel<1, 768><<<M, 256, 0, stream>>>(x_bf, ln0w, ln0b, xn_bf, 1e-5f);
  gemm_bt<0, 0><<<dim3(16, 32), 256, 0, stream>>>(xn_bf, gwbf, gh, nullptr, M,
                                                  2048, 768);
  gemm_bt<0, 0><<<dim3(8, 32), 256, 0, stream>>>(x_bf, rwbf, r0, nullptr, M,
                                                 1024, 768);
  scan_compose<<<dim3(32, 8), 256, 0, stream>>>(gh, Acl, Vcl);
  scan_prefix<<<8, 256, 0, stream>>>(Acl, Vcl, Hin);
  scan_emit<<<dim3(32, 8), 256, 0, stream>>>(gh, Hin, r0, x_f);

  // ---- layer 1 (identity residual) ----
  cvt(g1W, gwbf, 2048 * 1024);
  ln_kernel<0, 1024><<<M, 256, 0, stream>>>(x_f, ln1w, ln1b, xn_bf, 1e-5f);
  gemm_bt<0, 0><<<dim3(16, 32), 256, 0, stream>>>(xn_bf, gwbf, gh, nullptr, M,
                                                  2048, 1024);
  scan_compose<<<dim3(32, 8), 256, 0, stream>>>(gh, Acl, Vcl);
  scan_prefix<<<8, 256, 0, stream>>>(Acl, Vcl, Hin);
  scan_emit<<<dim3(32, 8), 256, 0, stream>>>(gh, Hin, x_f, x_f);

  // ---- layer 2 (identity residual) ----
  cvt(g2W, gwbf, 2048 * 1024);
  ln_kernel<0, 1024><<<M, 256, 0, stream>>>(x_f, ln2w, ln2b, xn_bf, 1e-5f);
  gemm_bt<0, 0><<<dim3(16, 32), 256, 0, stream>>>(xn_bf, gwbf, gh, nullptr, M,
                                                  2048, 1024);
  scan_compose<<<dim3(32, 8), 256, 0, stream>>>(gh, Acl, Vcl);
  scan_prefix<<<8, 256, 0, stream>>>(Acl, Vcl, Hin);
  scan_emit<<<dim3(32, 8), 256, 0, stream>>>(gh, Hin, x_f, x_f);

  // ---- final LN (eps=0) + vocab GEMM with bias, fp32 out ----
  // ROWFAST grid: x = 32 row-blocks (fastest), y = 393 col-blocks.
  ln_kernel<0, 1024><<<M, 256, 0, stream>>>(x_f, lnfw, lnfb, xn_bf, 0.0f);
  gemm_bt<1, 1><<<dim3(32, (V + 127) / 128), 256, 0, stream>>>(
      xn_bf, fcwbf, out, fcb, M, V, 1024);
}